// Round 10
// baseline (90.165 us; speedup 1.0000x reference)
//
#include <hip/hip_runtime.h>

// DiversityLoss: pose (K=32, B=32, T=64, E=63) fp32.
// feat[bt,k,e] = pose[k, b, t, e], bt = b*64+t.
// loss = sum_{bt} sum_{i<j} exp(-L1(feat[bt,i], feat[bt,j])) / (BT*K*(K-1)/2)
// Off-diagonal sum computed directly (both triangles, then halve) — diagonal
// exp(0)=1 terms would absorb the ~1e-18 off-diagonal terms in fp32.
//
// Structure: R3 winner (1 slice/block, 256 thr, 4 waves e-split, 4x4 tile,
// float4 exchange aliasing the feat tile, two kernels) with ONE change:
// inner loop holds a[4] but only ONE b float4 at a time -> live set ~56 VGPR
// (was 68), enabling __launch_bounds__(256, 8) -> VGPR cap 64 WITHOUT spills
// -> 8 blocks/CU (vs 7): all 2048 blocks resident, no straggler tail,
// 8 waves/SIMD hiding the cold-HBM staging latency (poison fills evict L3
// between replays, so staging is HBM-cold every timed call).
// LESSONS ENCODED: VGPR cap below live set -> 330 MB spill traffic (R5);
// single-address global accumulation -> +20 us serialization (R4: ACQ_REL
// 54 us; R9: relaxed atomicAdd 40 us) -> keep two kernels, no atomics;
// 1 slice/block beats 2 (R6-R8); LDS traffic is not the limiter (R8).

#define KDIM 32
#define EDIM 63
#define STRIDE 68      // feat row stride (dwords): 16B-aligned; 68%32=4 spreads rows over banks
#define BT_TOTAL 2048
#define CNT 1015808.0f // 2048 * 32*31/2

__global__ __launch_bounds__(256, 8) void divloss_pairs(const float* __restrict__ pose,
                                                        float* __restrict__ ws) {
    // 16 KB: feat tile (32*68 = 2176 dw) aliases part4 (16*64 float4 = 4096 dw).
    __shared__ float smem[4096];
    __shared__ float wsum[4];
    float* feat = smem;
    float4* part4 = reinterpret_cast<float4*>(smem);

    const int bt = blockIdx.x;
    const int wv = threadIdx.x >> 6;    // 0..3
    const int lane = threadIdx.x & 63;  // 0..63

    // Stage feat[bt]: wave wv loads rows 8*wv .. 8*wv+7 (63 floats, pad e=63 with 0).
    #pragma unroll
    for (int r = 0; r < 8; ++r) {
        const int k = 8 * wv + r;
        float v = 0.0f;
        if (lane < EDIM) v = pose[(k * BT_TOTAL + bt) * EDIM + lane];
        feat[k * STRIDE + lane] = v;
    }
    __syncthreads();

    const int ti = lane >> 3;   // rows {ti, ti+8, ti+16, ti+24}
    const int tj = lane & 7;    // cols {tj, tj+8, tj+16, tj+24}

    float acc[4][4] = {};

    // Wave wv covers e-chunks 4*wv .. 4*wv+3 (16 e-elems; wave 3 has the pad).
    // b loaded one float4 at a time to keep live VGPR <= 64 (8 waves/SIMD).
    #pragma unroll
    for (int i = 0; i < 4; ++i) {
        const int ec = 4 * wv + i;
        float4 a[4];
        #pragma unroll
        for (int r = 0; r < 4; ++r)
            a[r] = *reinterpret_cast<const float4*>(&feat[(ti + 8 * r) * STRIDE + 4 * ec]);
        #pragma unroll
        for (int c = 0; c < 4; ++c) {
            float4 b = *reinterpret_cast<const float4*>(&feat[(tj + 8 * c) * STRIDE + 4 * ec]);
            #pragma unroll
            for (int r = 0; r < 4; ++r) {
                acc[r][c] += fabsf(a[r].x - b.x) + fabsf(a[r].y - b.y)
                           + fabsf(a[r].z - b.z) + fabsf(a[r].w - b.w);
            }
        }
    }

    __syncthreads();   // all feat reads done; safe to overwrite with partials

    // Exchange: wave wv writes acc[r][0..3] as one float4 at entry (wv*4+r).
    // Lane stride 16B -> conflict-free ds_write_b128.
    #pragma unroll
    for (int r = 0; r < 4; ++r)
        part4[(wv * 4 + r) * 64 + lane] = make_float4(acc[r][0], acc[r][1], acc[r][2], acc[r][3]);
    __syncthreads();

    // Wave wv finalizes acc-row r=wv: d[c] = sum of the 4 waves' partials;
    // exp; mask diagonal pairs (ti==tj && c==wv); accumulate both triangles.
    float d0 = 0.f, d1 = 0.f, d2 = 0.f, d3 = 0.f;
    #pragma unroll
    for (int sw = 0; sw < 4; ++sw) {
        float4 v = part4[(sw * 4 + wv) * 64 + lane];
        d0 += v.x; d1 += v.y; d2 += v.z; d3 += v.w;
    }
    float s = 0.0f;
    {
        float e0 = __expf(-d0), e1 = __expf(-d1), e2 = __expf(-d2), e3 = __expf(-d3);
        s += ((ti == tj) && (wv == 0)) ? 0.0f : e0;
        s += ((ti == tj) && (wv == 1)) ? 0.0f : e1;
        s += ((ti == tj) && (wv == 2)) ? 0.0f : e2;
        s += ((ti == tj) && (wv == 3)) ? 0.0f : e3;
    }

    #pragma unroll
    for (int off = 32; off > 0; off >>= 1) s += __shfl_down(s, off, 64);
    if (lane == 0) wsum[wv] = s;
    __syncthreads();

    if (threadIdx.x == 0)
        ws[bt] = 0.5f * (wsum[0] + wsum[1] + wsum[2] + wsum[3]);
}

__global__ __launch_bounds__(256) void divloss_reduce(const float* __restrict__ ws,
                                                      float* __restrict__ out) {
    __shared__ float partial[4];
    const float4* w4 = reinterpret_cast<const float4*>(ws);  // 512 float4
    float4 v0 = w4[threadIdx.x];
    float4 v1 = w4[threadIdx.x + 256];
    float s = (v0.x + v0.y + v0.z + v0.w) + (v1.x + v1.y + v1.z + v1.w);
    #pragma unroll
    for (int off = 32; off > 0; off >>= 1) s += __shfl_down(s, off, 64);
    const int wave = threadIdx.x >> 6;
    if ((threadIdx.x & 63) == 0) partial[wave] = s;
    __syncthreads();
    if (threadIdx.x == 0) {
        float t = partial[0] + partial[1] + partial[2] + partial[3];
        out[0] = t * (1.0f / CNT);
    }
}

extern "C" void kernel_launch(void* const* d_in, const int* in_sizes, int n_in,
                              void* d_out, int out_size, void* d_ws, size_t ws_size,
                              hipStream_t stream) {
    const float* pose = (const float*)d_in[0];
    float* out = (float*)d_out;
    float* ws = (float*)d_ws;   // needs 2048 * 4 B

    divloss_pairs<<<BT_TOTAL, 256, 0, stream>>>(pose, ws);
    divloss_reduce<<<1, 256, 0, stream>>>(ws, out);
}

// Round 11
// 16.366 us; speedup vs baseline: 5.5092x; 5.5092x over previous
//
#include <hip/hip_runtime.h>

// DiversityLoss: pose (K=32, B=32, T=64, E=63) fp32.
// feat[bt,k,e] = pose[k, b, t, e], bt = b*64+t.
// loss = sum_{bt} sum_{i<j} exp(-L1(feat[bt,i], feat[bt,j])) / (BT*K*(K-1)/2)
// Off-diagonal sum computed directly (both triangles, then halve) — diagonal
// exp(0)=1 terms would absorb the ~1e-18 off-diagonal terms in fp32.
//
// EXACT round-3 configuration (best measured: 16.7 us) — A/A re-run to pin
// the noise band. 1 block (256 thr, 4 waves) per bt slice; waves split the
// e-dim (16 elems each); 4x4 register tile (0.5 LDS-reads/pair); scalar
// partial exchange aliasing the feat tile; two kernels, no atomics.
// LESSONS ENCODED (do not revisit):
//  - NO __launch_bounds__ min-waves: R5 (cap 64 -> 330 MB spill, 79 us),
//    R10 (cap -> VGPR 32, 360 MB spill traffic, 90 us). Live set ~68 VGPR.
//  - NO single-address global accumulation: R4 (agent ACQ_REL, 54 us),
//    R9 (relaxed atomicAdd, 40 us) — ~15 ns serialized RMW x 2048 blocks.
//  - 1 slice/block >= 2 slices/block (R6-R8); LDS traffic not the limiter
//    (R8: -25% reads = noise); exchange style = noise (R3 vs R6).

#define KDIM 32
#define EDIM 63
#define STRIDE 68      // feat row stride (dwords): 16B-aligned; 68%32=4 spreads rows over banks
#define BT_TOTAL 2048
#define CNT 1015808.0f // 2048 * 32*31/2

__global__ __launch_bounds__(256) void divloss_pairs(const float* __restrict__ pose,
                                                     float* __restrict__ ws) {
    // 16 KB: feat tile (32*68 = 2176 dw) aliases part (4096 dw) after a sync.
    __shared__ float smem[4096];
    __shared__ float wsum[4];
    float* feat = smem;
    float* part = smem;

    const int bt = blockIdx.x;
    const int wv = threadIdx.x >> 6;    // 0..3
    const int lane = threadIdx.x & 63;  // 0..63

    // Stage feat[bt]: wave wv loads rows 8*wv .. 8*wv+7 (63 floats, pad e=63 with 0).
    #pragma unroll
    for (int r = 0; r < 8; ++r) {
        const int k = 8 * wv + r;
        float v = 0.0f;
        if (lane < EDIM) v = pose[(k * BT_TOTAL + bt) * EDIM + lane];
        feat[k * STRIDE + lane] = v;
    }
    __syncthreads();

    const int ti = lane >> 3;   // rows {ti, ti+8, ti+16, ti+24}
    const int tj = lane & 7;    // cols {tj, tj+8, tj+16, tj+24}

    float acc[4][4];
    #pragma unroll
    for (int r = 0; r < 4; ++r)
        #pragma unroll
        for (int c = 0; c < 4; ++c) acc[r][c] = 0.0f;

    // Wave wv covers e-chunks 4*wv .. 4*wv+3 (16 e-elems; wave 3 has the pad).
    #pragma unroll
    for (int i = 0; i < 4; ++i) {
        const int ec = 4 * wv + i;
        float4 a[4], b[4];
        #pragma unroll
        for (int r = 0; r < 4; ++r)
            a[r] = *reinterpret_cast<const float4*>(&feat[(ti + 8 * r) * STRIDE + 4 * ec]);
        #pragma unroll
        for (int c = 0; c < 4; ++c)
            b[c] = *reinterpret_cast<const float4*>(&feat[(tj + 8 * c) * STRIDE + 4 * ec]);
        #pragma unroll
        for (int r = 0; r < 4; ++r)
            #pragma unroll
            for (int c = 0; c < 4; ++c) {
                acc[r][c] += fabsf(a[r].x - b[c].x) + fabsf(a[r].y - b[c].y)
                           + fabsf(a[r].z - b[c].z) + fabsf(a[r].w - b[c].w);
            }
    }

    __syncthreads();   // all feat reads done; safe to overwrite with partials

    // part[entry e=r*4+c][src wave][lane] — stride-1 across lanes, conflict-free.
    #pragma unroll
    for (int r = 0; r < 4; ++r)
        #pragma unroll
        for (int c = 0; c < 4; ++c)
            part[((r * 4 + c) * 4 + wv) * 64 + lane] = acc[r][c];
    __syncthreads();

    // Wave wv finalizes entries r=wv, c=0..3: sum the 4 per-wave partials,
    // exp, mask diagonal pairs (i==j <=> ti==tj && c==wv), accumulate.
    float s = 0.0f;
    #pragma unroll
    for (int c = 0; c < 4; ++c) {
        float d = 0.0f;
        #pragma unroll
        for (int sw = 0; sw < 4; ++sw)
            d += part[((wv * 4 + c) * 4 + sw) * 64 + lane];
        float e = __expf(-d);
        s += ((ti == tj) && (c == wv)) ? 0.0f : e;
    }

    #pragma unroll
    for (int off = 32; off > 0; off >>= 1) s += __shfl_down(s, off, 64);
    if (lane == 0) wsum[wv] = s;
    __syncthreads();

    if (threadIdx.x == 0)
        ws[bt] = 0.5f * (wsum[0] + wsum[1] + wsum[2] + wsum[3]);
}

__global__ __launch_bounds__(256) void divloss_reduce(const float* __restrict__ ws,
                                                      float* __restrict__ out) {
    __shared__ float partial[4];
    float s = 0.0f;
    for (int i = threadIdx.x; i < BT_TOTAL; i += 256) s += ws[i];
    #pragma unroll
    for (int off = 32; off > 0; off >>= 1) s += __shfl_down(s, off, 64);
    const int wave = threadIdx.x >> 6;
    if ((threadIdx.x & 63) == 0) partial[wave] = s;
    __syncthreads();
    if (threadIdx.x == 0) {
        float t = partial[0] + partial[1] + partial[2] + partial[3];
        out[0] = t * (1.0f / CNT);
    }
}

extern "C" void kernel_launch(void* const* d_in, const int* in_sizes, int n_in,
                              void* d_out, int out_size, void* d_ws, size_t ws_size,
                              hipStream_t stream) {
    const float* pose = (const float*)d_in[0];
    float* out = (float*)d_out;
    float* ws = (float*)d_ws;   // needs 2048 * 4 B

    divloss_pairs<<<BT_TOTAL, 256, 0, stream>>>(pose, ws);
    divloss_reduce<<<1, 256, 0, stream>>>(ws, out);
}